// Round 6
// baseline (861.948 us; speedup 1.0000x reference)
//
#include <hip/hip_runtime.h>
#include <hip/hip_bf16.h>

// ---------- problem constants ----------
constexpr int Nrows = 8192;   // batch rows
constexpr int L     = 256;    // input_len / features
constexpr int D     = 128;    // hidden per head
constexpr float EPS = 1e-5f;

typedef __bf16 bf16x8 __attribute__((ext_vector_type(8)));
typedef __bf16 bf16x4 __attribute__((ext_vector_type(4)));
typedef float  f32x4  __attribute__((ext_vector_type(4)));
typedef short  s16x4  __attribute__((ext_vector_type(4)));

#define MFMA16(a, b, c) __builtin_amdgcn_mfma_f32_16x16x32_bf16((a), (b), (c), 0, 0, 0)

// K=16 bf16 MFMA: builtin when available, else inline asm (gfx950 has the
// instruction per ISA; s_nop guards the VALU->MFMA operand hazard).
#if __has_builtin(__builtin_amdgcn_mfma_f32_16x16x16bf16_1k)
#define MFMA_K16(A_, B_, C_) (C_) = __builtin_amdgcn_mfma_f32_16x16x16bf16_1k((A_), (B_), (C_), 0, 0, 0)
#else
#define MFMA_K16(A_, B_, C_) asm volatile("s_nop 1\n\tv_mfma_f32_16x16x16_bf16 %0, %1, %2, %0" : "+v"(C_) : "v"(A_), "v"(B_))
#endif

// ============================================================
// param convert+transpose (fp32 -> bf16):
//   Bt[6][128][256]: Bt[g][d][l] = P_g[l*128+d], P_g in {Q0,K0,Vd0,Q1,K1,Vd1}
//   VupT[2][256][128]: VupT[h][l][d] = Vup[h][d][l]
//   Wb[2][256][256]: straight bf16 copy of W
// ============================================================
__global__ void k_cvt_params(const float* __restrict__ Q, const float* __restrict__ K,
                             const float* __restrict__ Vd, const float* __restrict__ Vup,
                             const float* __restrict__ W,
                             __bf16* __restrict__ Bt, __bf16* __restrict__ VupT,
                             __bf16* __restrict__ Wb) {
    int i = blockIdx.x * 256 + threadIdx.x;
    if (i < 6 * 128 * 256) {
        int g = i >> 15; int r = i & 32767; int d = r >> 8; int l = r & 255;
        const float* src = (g % 3 == 0 ? Q : (g % 3 == 1 ? K : Vd)) + (g / 3) * (L * D);
        Bt[i] = (__bf16)src[l * D + d];
    } else if (i < 8 * 128 * 256) {
        int j = i - 6 * 128 * 256;               // [0, 65536)
        int h = j >> 15; int r = j & 32767; int l = r >> 7; int d = r & 127;
        VupT[j] = (__bf16)Vup[h * (D * L) + d * L + l];
    } else {
        int j = i - 8 * 128 * 256;               // [0, 131072)
        Wb[j] = (__bf16)W[j];
    }
}

// ============================================================
// batchnorm stats: per-column sum / sumsq over 8192 rows (fp32 input)
// ============================================================
__global__ void k_bn_stats(const float* __restrict__ x, float* __restrict__ sum,
                           float* __restrict__ sq) {
    int col = threadIdx.x;                        // 256 columns
    int r0 = blockIdx.x * 64;                     // 128 blocks x 64 rows
    float s = 0.f, s2 = 0.f;
    for (int i = 0; i < 64; i++) {
        float v = x[(r0 + i) * L + col];
        s += v; s2 += v * v;
    }
    atomicAdd(&sum[col], s);
    atomicAdd(&sq[col], s2);
}

// ============================================================
// batchnorm normalize: bn1 emits bf16 (for GEMMs) + fp32 (residual)
// ============================================================
__global__ void k_bn_norm1(const float* __restrict__ x, const float* __restrict__ sum,
                           const float* __restrict__ sq, __bf16* __restrict__ hb,
                           float* __restrict__ hf) {
    int i = (blockIdx.x * 256 + threadIdx.x) * 4;
    int col = i & (L - 1);
    f32x4 v = *(const f32x4*)(x + i);
    bf16x4 o; f32x4 of;
#pragma unroll
    for (int j = 0; j < 4; j++) {
        float m   = sum[col + j] * (1.0f / Nrows);
        float var = sq[col + j] * (1.0f / Nrows) - m * m;
        float rs  = rsqrtf(var + EPS);
        float t = (v[j] - m) * rs;
        of[j] = t; o[j] = (__bf16)t;
    }
    *(bf16x4*)(hb + i) = o;
    *(f32x4*)(hf + i) = of;
}

__global__ void k_bn_norm2(const float* __restrict__ z, const float* __restrict__ sum,
                           const float* __restrict__ sq, __bf16* __restrict__ h) {
    int i = (blockIdx.x * 256 + threadIdx.x) * 4;
    int col = i & (L - 1);
    f32x4 v = *(const f32x4*)(z + i);
    bf16x4 o;
#pragma unroll
    for (int j = 0; j < 4; j++) {
        float m   = sum[col + j] * (1.0f / Nrows);
        float var = sq[col + j] * (1.0f / Nrows) - m * m;
        float rs  = rsqrtf(var + EPS);
        o[j] = (__bf16)((v[j] - m) * rs);
    }
    *(bf16x4*)(h + i) = o;
}

// ============================================================
// QKV projection: q/k row-major [8192][128]; v TRANSPOSED Vt[head][128][8192]
// ============================================================
__launch_bounds__(256)
__global__ void k_gemm_qkv(const __bf16* __restrict__ h, const __bf16* __restrict__ Bt,
                           __bf16* __restrict__ q0, __bf16* __restrict__ k0,
                           __bf16* __restrict__ q1, __bf16* __restrict__ k1,
                           __bf16* __restrict__ Vt) {
    int g = blockIdx.y;                 // 0..5
    int m0 = blockIdx.x * 128;
    int w = threadIdx.x >> 6, lane = threadIdx.x & 63;
    int c = lane & 15, qd = lane >> 4;
    int mw = m0 + w * 32;
    const __bf16* B = Bt + g * (128 * 256);

    f32x4 acc[2][8] = {};
#pragma unroll
    for (int kc = 0; kc < 8; kc++) {
        bf16x8 a0 = *(const bf16x8*)(h + (mw + c) * L + kc * 32 + qd * 8);
        bf16x8 a1 = *(const bf16x8*)(h + (mw + 16 + c) * L + kc * 32 + qd * 8);
#pragma unroll
        for (int nt = 0; nt < 8; nt++) {
            bf16x8 b = *(const bf16x8*)(B + (nt * 16 + c) * L + kc * 32 + qd * 8);
            acc[0][nt] = MFMA16(a0, b, acc[0][nt]);
            acc[1][nt] = MFMA16(a1, b, acc[1][nt]);
        }
    }
    if (g == 2 || g == 5) {
        __bf16* vt = Vt + (g / 3) * (128 * Nrows);
#pragma unroll
        for (int mt = 0; mt < 2; mt++)
#pragma unroll
            for (int nt = 0; nt < 8; nt++)
#pragma unroll
                for (int r = 0; r < 4; r++) {
                    int row = mw + mt * 16 + 4 * qd + r;   // n (sequence) index
                    int colv = nt * 16 + c;                // d index
                    vt[colv * Nrows + row] = (__bf16)acc[mt][nt][r];
                }
    } else {
        __bf16* dst = (g == 0) ? q0 : (g == 1) ? k0 : (g == 3) ? q1 : k1;
#pragma unroll
        for (int mt = 0; mt < 2; mt++)
#pragma unroll
            for (int nt = 0; nt < 8; nt++)
#pragma unroll
                for (int r = 0; r < 4; r++) {
                    int row = mw + mt * 16 + 4 * qd + r;
                    int colv = nt * 16 + c;
                    dst[row * D + colv] = (__bf16)acc[mt][nt][r];
                }
    }
}

// ============================================================
// Flash attention, LDS-FREE main loop (swapped-QK^T / T12):
//   S^T = MFMA(K, Q): lane holds P^T[key=4qd+r][q=c]; those 4 r-contiguous
//   keys ARE the B-fragment of the K=16 MFMA (k = qd*4+j), so after exp +
//   bf16 pack, P feeds PV directly from registers. PV computes
//   O^T[d][q] via A=V^T fragments (8B loads from Vt[d][seq]).
//   No ds_write/ds_read/barrier in the loop. l is a per-lane scalar.
// 8 waves x 512 thr, grid 256 (1 block/CU, 2 waves/SIMD).
// amdgpu_waves_per_eu(2,2): pin regalloc to the occupancy the grid
// actually delivers (2 waves/SIMD -> 256-VGPR cap). Without it the
// backend targeted ~4 waves/SIMD, allocated 116 VGPRs and spilled the
// ~196-reg live set to scratch every iteration (r5: 693us, all idle).
// ============================================================
__attribute__((amdgpu_waves_per_eu(2, 2)))
__launch_bounds__(512)
__global__ void k_flash(const __bf16* __restrict__ q0, const __bf16* __restrict__ k0,
                        const __bf16* __restrict__ q1, const __bf16* __restrict__ k1,
                        const __bf16* __restrict__ Vt, __bf16* __restrict__ O) {
    int head = blockIdx.x & 1;
    int qtile = blockIdx.x >> 1;       // 0..127
    int m0 = qtile * 64;
    const __bf16* qm = head ? q1 : q0;
    const __bf16* km = head ? k1 : k0;
    const __bf16* vt = Vt + head * (128 * Nrows);
    __bf16* Og = O + head * (Nrows * D);

    int w = threadIdx.x >> 6;          // 0..7
    int qh = w >> 1;                   // q-subtile 0..3
    int ks = w & 1;                    // key-slice 0/1
    int lane = threadIdx.x & 63;
    int c = lane & 15, qd = lane >> 4;
    int mq = m0 + qh * 16;             // wave's 16 q rows

    __shared__ float obuf[4][16][136]; // ks=1 partial O^T dump (pad: 136*4B=16B-mult)
    __shared__ float lred[8][16];

    // Q as B-fragment: B[d][q=c]
    bf16x8 aq[4];
#pragma unroll
    for (int kc = 0; kc < 4; kc++)
        aq[kc] = *(const bf16x8*)(qm + (mq + c) * D + kc * 32 + qd * 8);

    f32x4 oacc[8] = {};                // O^T: d = dvt*16+4qd+r, q = mq+c
    float lp = 0.f;                    // softmax denom partial for q = mq+c

    auto loadk = [&](bf16x8 (&kb)[2][4], int n0) {
        int nb = n0 + ks * 32;
#pragma unroll
        for (int nt = 0; nt < 2; nt++)
#pragma unroll
            for (int kc = 0; kc < 4; kc++)
                kb[nt][kc] = *(const bf16x8*)(km + (nb + nt * 16 + c) * D + kc * 32 + qd * 8);
    };
    auto loadv = [&](s16x4 (&vb)[8][2], int n0) {
        int nb = n0 + ks * 32;
#pragma unroll
        for (int dvt = 0; dvt < 8; dvt++)
#pragma unroll
            for (int nt = 0; nt < 2; nt++)
                vb[dvt][nt] = *(const s16x4*)(vt + (dvt * 16 + c) * Nrows + nb + nt * 16 + qd * 4);
    };
    auto compute = [&](const bf16x8 (&kb)[2][4], const s16x4 (&vb)[8][2]) {
#pragma unroll
        for (int nt = 0; nt < 2; nt++) {
            f32x4 s = {};
            __builtin_amdgcn_s_setprio(1);
#pragma unroll
            for (int kc = 0; kc < 4; kc++) s = MFMA16(kb[nt][kc], aq[kc], s);
            __builtin_amdgcn_s_setprio(0);
            float e0 = __expf(s[0]), e1 = __expf(s[1]);
            float e2 = __expf(s[2]), e3 = __expf(s[3]);
            lp += (e0 + e1) + (e2 + e3);
            bf16x4 pbv; pbv[0] = (__bf16)e0; pbv[1] = (__bf16)e1;
            pbv[2] = (__bf16)e2; pbv[3] = (__bf16)e3;
            s16x4 pb = __builtin_bit_cast(s16x4, pbv);
            __builtin_amdgcn_s_setprio(1);
#pragma unroll
            for (int dvt = 0; dvt < 8; dvt++) MFMA_K16(vb[dvt][nt], pb, oacc[dvt]);
            __builtin_amdgcn_s_setprio(0);
        }
    };

    bf16x8 kbA[2][4], kbB[2][4];
    s16x4  vbA[8][2], vbB[8][2];
    loadk(kbA, 0); loadv(vbA, 0);
    for (int n0 = 0; n0 < Nrows; n0 += 128) {
        loadk(kbB, n0 + 64); loadv(vbB, n0 + 64);     // prefetch next 64-key tile
        compute(kbA, vbA);
        if (n0 + 128 < Nrows) { loadk(kbA, n0 + 128); loadv(vbA, n0 + 128); }
        compute(kbB, vbB);
    }
    asm volatile("s_nop 7\n\ts_nop 7" ::: "memory");  // MFMA->VALU hazard guard (asm path)

    // l: sum the 4 qd-lanes of each q column
    float lv = lp;
    lv += __shfl_xor(lv, 16);
    lv += __shfl_xor(lv, 32);
    if (lane < 16) lred[w][lane] = lv;                // lane==c for qd==0
    if (ks == 1) {
#pragma unroll
        for (int dvt = 0; dvt < 8; dvt++)
            *(f32x4*)&obuf[qh][c][dvt * 16 + qd * 4] = oacc[dvt];
    }
    __syncthreads();
    if (ks == 0) {
        float il = 1.0f / (lred[w][c] + lred[w + 1][c]);
#pragma unroll
        for (int dvt = 0; dvt < 8; dvt++) {
            f32x4 v = oacc[dvt] + *(const f32x4*)&obuf[qh][c][dvt * 16 + qd * 4];
            bf16x4 o;
#pragma unroll
            for (int e = 0; e < 4; e++) o[e] = (__bf16)(v[e] * il);
            *(bf16x4*)(Og + (mq + c) * D + dvt * 16 + qd * 4) = o;
        }
    }
}

// ============================================================
// z = hf + O0 @ Vup0 + O1 @ Vup1   (fp32 residual + fp32 out)
// ============================================================
__launch_bounds__(256)
__global__ void k_gemm_vup(const __bf16* __restrict__ O, const __bf16* __restrict__ VupT,
                           const float* __restrict__ hf, float* __restrict__ z) {
    int n0 = blockIdx.y * 128;
    int m0 = blockIdx.x * 128;
    int w = threadIdx.x >> 6, lane = threadIdx.x & 63;
    int c = lane & 15, qd = lane >> 4;
    int mw = m0 + w * 32;

    f32x4 acc[2][8] = {};
#pragma unroll
    for (int kc = 0; kc < 8; kc++) {
        const __bf16* Oh = O + (kc >> 2) * (Nrows * D);
        const __bf16* Vh = VupT + (kc >> 2) * (L * D);
        int ko = (kc & 3) * 32 + qd * 8;
        bf16x8 a0 = *(const bf16x8*)(Oh + (mw + c) * D + ko);
        bf16x8 a1 = *(const bf16x8*)(Oh + (mw + 16 + c) * D + ko);
#pragma unroll
        for (int nt = 0; nt < 8; nt++) {
            bf16x8 b = *(const bf16x8*)(Vh + (n0 + nt * 16 + c) * D + ko);
            acc[0][nt] = MFMA16(a0, b, acc[0][nt]);
            acc[1][nt] = MFMA16(a1, b, acc[1][nt]);
        }
    }
#pragma unroll
    for (int mt = 0; mt < 2; mt++)
#pragma unroll
        for (int nt = 0; nt < 8; nt++)
#pragma unroll
            for (int r = 0; r < 4; r++) {
                int row = mw + mt * 16 + 4 * qd + r;
                int col = n0 + nt * 16 + c;
                z[row * L + col] = acc[mt][nt][r] + hf[row * L + col];
            }
}

// ============================================================
// out = relu(hin @ W^T + b); OutT = __bf16 (intermediate) or float (final)
// ============================================================
template <typename OutT>
__launch_bounds__(256)
__global__ void k_gemm_w(const __bf16* __restrict__ hin, const __bf16* __restrict__ W,
                         const float* __restrict__ bias, OutT* __restrict__ out) {
    int n0 = blockIdx.y * 128;
    int m0 = blockIdx.x * 128;
    int w = threadIdx.x >> 6, lane = threadIdx.x & 63;
    int c = lane & 15, qd = lane >> 4;
    int mw = m0 + w * 32;

    f32x4 acc[2][8] = {};
#pragma unroll
    for (int kc = 0; kc < 8; kc++) {
        bf16x8 a0 = *(const bf16x8*)(hin + (mw + c) * L + kc * 32 + qd * 8);
        bf16x8 a1 = *(const bf16x8*)(hin + (mw + 16 + c) * L + kc * 32 + qd * 8);
#pragma unroll
        for (int nt = 0; nt < 8; nt++) {
            bf16x8 b = *(const bf16x8*)(W + (n0 + nt * 16 + c) * L + kc * 32 + qd * 8);
            acc[0][nt] = MFMA16(a0, b, acc[0][nt]);
            acc[1][nt] = MFMA16(a1, b, acc[1][nt]);
        }
    }
#pragma unroll
    for (int mt = 0; mt < 2; mt++)
#pragma unroll
        for (int nt = 0; nt < 8; nt++) {
            int col = n0 + nt * 16 + c;
            float bv = bias[col];
#pragma unroll
            for (int r = 0; r < 4; r++) {
                int row = mw + mt * 16 + 4 * qd + r;
                float v = fmaxf(acc[mt][nt][r] + bv, 0.0f);
                out[row * L + col] = (OutT)v;
            }
        }
}

// ============================================================
extern "C" void kernel_launch(void* const* d_in, const int* in_sizes, int n_in,
                              void* d_out, int out_size, void* d_ws, size_t ws_size,
                              hipStream_t stream) {
    (void)in_sizes; (void)n_in; (void)out_size; (void)ws_size;
    const float* x   = (const float*)d_in[0];
    const float* Q   = (const float*)d_in[1];
    const float* K   = (const float*)d_in[2];
    const float* Vd  = (const float*)d_in[3];
    const float* Vup = (const float*)d_in[4];
    const float* W   = (const float*)d_in[5];
    const float* b   = (const float*)d_in[6];
    float* out = (float*)d_out;

    char* ws = (char*)d_ws;
    size_t off = 0;
    auto alloc = [&](size_t bytes) -> void* {
        void* p = ws + off;
        off += (bytes + 255) & ~(size_t)255;
        return p;
    };
    float*  stats = (float*)alloc(4 * 256 * sizeof(float)); // sum1,sq1,sum2,sq2
    __bf16* Bt    = (__bf16*)alloc(6 * 128 * 256 * 2);
    __bf16* VupT  = (__bf16*)alloc(2 * 256 * 128 * 2);
    __bf16* Wb    = (__bf16*)alloc(2 * 256 * 256 * 2);
    __bf16* hb    = (__bf16*)alloc((size_t)Nrows * L * 2);
    float*  hf    = (float*)alloc((size_t)Nrows * L * 4);
    __bf16* q0    = (__bf16*)alloc((size_t)Nrows * D * 2);
    __bf16* k0    = (__bf16*)alloc((size_t)Nrows * D * 2);
    __bf16* q1    = (__bf16*)alloc((size_t)Nrows * D * 2);
    __bf16* k1    = (__bf16*)alloc((size_t)Nrows * D * 2);
    __bf16* Vt    = (__bf16*)alloc((size_t)2 * 128 * Nrows * 2);
    __bf16* O     = (__bf16*)alloc((size_t)2 * Nrows * D * 2);
    float*  z     = (float*)alloc((size_t)Nrows * L * 4);
    __bf16* h2    = (__bf16*)alloc((size_t)Nrows * L * 2);
    __bf16* h3    = (__bf16*)alloc((size_t)Nrows * L * 2);

    float* sum1 = stats, *sq1 = stats + 256, *sum2 = stats + 512, *sq2 = stats + 768;

    hipMemsetAsync(stats, 0, 4 * 256 * sizeof(float), stream);
    k_cvt_params<<<1536, 256, 0, stream>>>(Q, K, Vd, Vup, W, Bt, VupT, Wb);
    k_bn_stats<<<128, 256, 0, stream>>>(x, sum1, sq1);
    k_bn_norm1<<<2048, 256, 0, stream>>>(x, sum1, sq1, hb, hf);
    k_gemm_qkv<<<dim3(64, 6), 256, 0, stream>>>(hb, Bt, q0, k0, q1, k1, Vt);
    k_flash<<<256, 512, 0, stream>>>(q0, k0, q1, k1, Vt, O);
    k_gemm_vup<<<dim3(64, 2), 256, 0, stream>>>(O, VupT, hf, z);
    k_bn_stats<<<128, 256, 0, stream>>>(z, sum2, sq2);
    k_bn_norm2<<<2048, 256, 0, stream>>>(z, sum2, sq2, h2);
    k_gemm_w<__bf16><<<dim3(64, 2), 256, 0, stream>>>(h2, Wb, b, h3);
    k_gemm_w<float><<<dim3(64, 2), 256, 0, stream>>>(h3, Wb + 256 * 256, b + 256, out);
}

// Round 7
// 524.130 us; speedup vs baseline: 1.6445x; 1.6445x over previous
//
#include <hip/hip_runtime.h>
#include <hip/hip_bf16.h>

// ---------- problem constants ----------
constexpr int Nrows = 8192;   // batch rows
constexpr int L     = 256;    // input_len / features
constexpr int D     = 128;    // hidden per head
constexpr float EPS = 1e-5f;

typedef __bf16 bf16x8 __attribute__((ext_vector_type(8)));
typedef __bf16 bf16x4 __attribute__((ext_vector_type(4)));
typedef float  f32x4  __attribute__((ext_vector_type(4)));
typedef short  s16x4  __attribute__((ext_vector_type(4)));

#define MFMA16(a, b, c) __builtin_amdgcn_mfma_f32_16x16x32_bf16((a), (b), (c), 0, 0, 0)

// K=16 bf16 MFMA: builtin when available, else inline asm (gfx950 has the
// instruction per ISA; s_nop guards the VALU->MFMA operand hazard).
#if __has_builtin(__builtin_amdgcn_mfma_f32_16x16x16bf16_1k)
#define MFMA_K16(A_, B_, C_) (C_) = __builtin_amdgcn_mfma_f32_16x16x16bf16_1k((A_), (B_), (C_), 0, 0, 0)
#else
#define MFMA_K16(A_, B_, C_) asm volatile("s_nop 1\n\tv_mfma_f32_16x16x16_bf16 %0, %1, %2, %0" : "+v"(C_) : "v"(A_), "v"(B_))
#endif

// ============================================================
// param convert+transpose (fp32 -> bf16):
//   Bt[6][128][256]: Bt[g][d][l] = P_g[l*128+d], P_g in {Q0,K0,Vd0,Q1,K1,Vd1}
//   VupT[2][256][128]: VupT[h][l][d] = Vup[h][d][l]
//   Wb[2][256][256]: straight bf16 copy of W
// ============================================================
__global__ void k_cvt_params(const float* __restrict__ Q, const float* __restrict__ K,
                             const float* __restrict__ Vd, const float* __restrict__ Vup,
                             const float* __restrict__ W,
                             __bf16* __restrict__ Bt, __bf16* __restrict__ VupT,
                             __bf16* __restrict__ Wb) {
    int i = blockIdx.x * 256 + threadIdx.x;
    if (i < 6 * 128 * 256) {
        int g = i >> 15; int r = i & 32767; int d = r >> 8; int l = r & 255;
        const float* src = (g % 3 == 0 ? Q : (g % 3 == 1 ? K : Vd)) + (g / 3) * (L * D);
        Bt[i] = (__bf16)src[l * D + d];
    } else if (i < 8 * 128 * 256) {
        int j = i - 6 * 128 * 256;               // [0, 65536)
        int h = j >> 15; int r = j & 32767; int l = r >> 7; int d = r & 127;
        VupT[j] = (__bf16)Vup[h * (D * L) + d * L + l];
    } else {
        int j = i - 8 * 128 * 256;               // [0, 131072)
        Wb[j] = (__bf16)W[j];
    }
}

// ============================================================
// batchnorm stats: per-column sum / sumsq over 8192 rows (fp32 input)
// ============================================================
__global__ void k_bn_stats(const float* __restrict__ x, float* __restrict__ sum,
                           float* __restrict__ sq) {
    int col = threadIdx.x;                        // 256 columns
    int r0 = blockIdx.x * 64;                     // 128 blocks x 64 rows
    float s = 0.f, s2 = 0.f;
    for (int i = 0; i < 64; i++) {
        float v = x[(r0 + i) * L + col];
        s += v; s2 += v * v;
    }
    atomicAdd(&sum[col], s);
    atomicAdd(&sq[col], s2);
}

// ============================================================
// batchnorm normalize: bn1 emits bf16 (for GEMMs) + fp32 (residual)
// ============================================================
__global__ void k_bn_norm1(const float* __restrict__ x, const float* __restrict__ sum,
                           const float* __restrict__ sq, __bf16* __restrict__ hb,
                           float* __restrict__ hf) {
    int i = (blockIdx.x * 256 + threadIdx.x) * 4;
    int col = i & (L - 1);
    f32x4 v = *(const f32x4*)(x + i);
    bf16x4 o; f32x4 of;
#pragma unroll
    for (int j = 0; j < 4; j++) {
        float m   = sum[col + j] * (1.0f / Nrows);
        float var = sq[col + j] * (1.0f / Nrows) - m * m;
        float rs  = rsqrtf(var + EPS);
        float t = (v[j] - m) * rs;
        of[j] = t; o[j] = (__bf16)t;
    }
    *(bf16x4*)(hb + i) = o;
    *(f32x4*)(hf + i) = of;
}

__global__ void k_bn_norm2(const float* __restrict__ z, const float* __restrict__ sum,
                           const float* __restrict__ sq, __bf16* __restrict__ h) {
    int i = (blockIdx.x * 256 + threadIdx.x) * 4;
    int col = i & (L - 1);
    f32x4 v = *(const f32x4*)(z + i);
    bf16x4 o;
#pragma unroll
    for (int j = 0; j < 4; j++) {
        float m   = sum[col + j] * (1.0f / Nrows);
        float var = sq[col + j] * (1.0f / Nrows) - m * m;
        float rs  = rsqrtf(var + EPS);
        o[j] = (__bf16)((v[j] - m) * rs);
    }
    *(bf16x4*)(h + i) = o;
}

// ============================================================
// QKV projection: q/k row-major [8192][128]; v TRANSPOSED Vt[head][128][8192]
// ============================================================
__launch_bounds__(256)
__global__ void k_gemm_qkv(const __bf16* __restrict__ h, const __bf16* __restrict__ Bt,
                           __bf16* __restrict__ q0, __bf16* __restrict__ k0,
                           __bf16* __restrict__ q1, __bf16* __restrict__ k1,
                           __bf16* __restrict__ Vt) {
    int g = blockIdx.y;                 // 0..5
    int m0 = blockIdx.x * 128;
    int w = threadIdx.x >> 6, lane = threadIdx.x & 63;
    int c = lane & 15, qd = lane >> 4;
    int mw = m0 + w * 32;
    const __bf16* B = Bt + g * (128 * 256);

    f32x4 acc[2][8] = {};
#pragma unroll
    for (int kc = 0; kc < 8; kc++) {
        bf16x8 a0 = *(const bf16x8*)(h + (mw + c) * L + kc * 32 + qd * 8);
        bf16x8 a1 = *(const bf16x8*)(h + (mw + 16 + c) * L + kc * 32 + qd * 8);
#pragma unroll
        for (int nt = 0; nt < 8; nt++) {
            bf16x8 b = *(const bf16x8*)(B + (nt * 16 + c) * L + kc * 32 + qd * 8);
            acc[0][nt] = MFMA16(a0, b, acc[0][nt]);
            acc[1][nt] = MFMA16(a1, b, acc[1][nt]);
        }
    }
    if (g == 2 || g == 5) {
        __bf16* vt = Vt + (g / 3) * (128 * Nrows);
#pragma unroll
        for (int mt = 0; mt < 2; mt++)
#pragma unroll
            for (int nt = 0; nt < 8; nt++)
#pragma unroll
                for (int r = 0; r < 4; r++) {
                    int row = mw + mt * 16 + 4 * qd + r;   // n (sequence) index
                    int colv = nt * 16 + c;                // d index
                    vt[colv * Nrows + row] = (__bf16)acc[mt][nt][r];
                }
    } else {
        __bf16* dst = (g == 0) ? q0 : (g == 1) ? k0 : (g == 3) ? q1 : k1;
#pragma unroll
        for (int mt = 0; mt < 2; mt++)
#pragma unroll
            for (int nt = 0; nt < 8; nt++)
#pragma unroll
                for (int r = 0; r < 4; r++) {
                    int row = mw + mt * 16 + 4 * qd + r;
                    int colv = nt * 16 + c;
                    dst[row * D + colv] = (__bf16)acc[mt][nt][r];
                }
    }
}

// ============================================================
// Flash attention, LDS-FREE main loop (swapped-QK^T / T12), 4-wave shape:
//   256 thr / 4 waves per block (NOT 512: the backend caps 8-wave
//   workgroups at 128 VGPRs and spills ~80 regs -> r5/r6 693us disaster;
//   4-wave blocks are granted ~232 VGPRs, r0/r3 precedent).
//   wave (qh, ks): 32 q rows (two 16-q groups) x 32-key slice.
//   S^T = MFMA(K, Q): lane holds P^T[key=4qd+r][q=c]; exp + bf16 pack
//   feeds the K=16 PV MFMA B-fragment directly from registers.
//   kb/vb are REUSED for both q-groups (x2 register efficiency vs r5).
//   K double-buffered; V single-buffered (WAR-serialized behind prev PV).
// ============================================================
__launch_bounds__(256, 1)
__global__ void k_flash(const __bf16* __restrict__ q0, const __bf16* __restrict__ k0,
                        const __bf16* __restrict__ q1, const __bf16* __restrict__ k1,
                        const __bf16* __restrict__ Vt, __bf16* __restrict__ O) {
    int head = blockIdx.x & 1;
    int qtile = blockIdx.x >> 1;       // 0..127
    int m0 = qtile * 64;
    const __bf16* qm = head ? q1 : q0;
    const __bf16* km = head ? k1 : k0;
    const __bf16* vt = Vt + head * (128 * Nrows);
    __bf16* Og = O + head * (Nrows * D);

    int w = threadIdx.x >> 6;          // 0..3
    int qh = w >> 1;                   // q-half 0/1 (32 rows each)
    int ks = w & 1;                    // key-slice 0/1
    int lane = threadIdx.x & 63;
    int c = lane & 15, qd = lane >> 4;
    int mq = m0 + qh * 32;             // wave's 32 q rows

    __shared__ float obuf[2][2][16][136]; // ks=1 partial O^T dump
    __shared__ float lred[4][2][16];

    // Q as B-fragment: B[d][q=c], two 16-q groups
    bf16x8 aq[2][4];
#pragma unroll
    for (int qg = 0; qg < 2; qg++)
#pragma unroll
        for (int kc = 0; kc < 4; kc++)
            aq[qg][kc] = *(const bf16x8*)(qm + (mq + qg * 16 + c) * D + kc * 32 + qd * 8);

    f32x4 oacc[2][8] = {};             // O^T per q-group: d = dvt*16+4qd+r, q = c
    float lp0 = 0.f, lp1 = 0.f;        // softmax denom partials (q = c per group)

    auto loadk = [&](bf16x8 (&kb)[2][4], int n0) {
        int nb = n0 + ks * 32;
#pragma unroll
        for (int nt = 0; nt < 2; nt++)
#pragma unroll
            for (int kc = 0; kc < 4; kc++)
                kb[nt][kc] = *(const bf16x8*)(km + (nb + nt * 16 + c) * D + kc * 32 + qd * 8);
    };
    auto loadv = [&](s16x4 (&vb)[8][2], int n0) {
        int nb = n0 + ks * 32;
#pragma unroll
        for (int dvt = 0; dvt < 8; dvt++)
#pragma unroll
            for (int nt = 0; nt < 2; nt++)
                vb[dvt][nt] = *(const s16x4*)(vt + (dvt * 16 + c) * Nrows + nb + nt * 16 + qd * 4);
    };
    auto compute = [&](const bf16x8 (&kb)[2][4], const s16x4 (&vb)[8][2]) {
#pragma unroll
        for (int nt = 0; nt < 2; nt++) {
            f32x4 s0 = {}, s1 = {};
            __builtin_amdgcn_s_setprio(1);
#pragma unroll
            for (int kc = 0; kc < 4; kc++) s0 = MFMA16(kb[nt][kc], aq[0][kc], s0);
#pragma unroll
            for (int kc = 0; kc < 4; kc++) s1 = MFMA16(kb[nt][kc], aq[1][kc], s1);
            __builtin_amdgcn_s_setprio(0);
            float a0 = __expf(s0[0]), a1 = __expf(s0[1]), a2 = __expf(s0[2]), a3 = __expf(s0[3]);
            float b0 = __expf(s1[0]), b1 = __expf(s1[1]), b2 = __expf(s1[2]), b3 = __expf(s1[3]);
            lp0 += (a0 + a1) + (a2 + a3);
            lp1 += (b0 + b1) + (b2 + b3);
            bf16x4 pav; pav[0] = (__bf16)a0; pav[1] = (__bf16)a1; pav[2] = (__bf16)a2; pav[3] = (__bf16)a3;
            bf16x4 pbv; pbv[0] = (__bf16)b0; pbv[1] = (__bf16)b1; pbv[2] = (__bf16)b2; pbv[3] = (__bf16)b3;
            s16x4 pa = __builtin_bit_cast(s16x4, pav);
            s16x4 pb = __builtin_bit_cast(s16x4, pbv);
            __builtin_amdgcn_s_setprio(1);
#pragma unroll
            for (int dvt = 0; dvt < 8; dvt++) {
                MFMA_K16(vb[dvt][nt], pa, oacc[0][dvt]);
                MFMA_K16(vb[dvt][nt], pb, oacc[1][dvt]);
            }
            __builtin_amdgcn_s_setprio(0);
        }
    };

    bf16x8 kbA[2][4], kbB[2][4];
    s16x4  vb[8][2];
    loadk(kbA, 0);
    for (int n0 = 0; n0 < Nrows; n0 += 128) {
        loadk(kbB, n0 + 64);             // prefetch next K tile
        loadv(vb, n0);                   // V for current tile
        compute(kbA, vb);
        if (n0 + 128 < Nrows) loadk(kbA, n0 + 128);
        loadv(vb, n0 + 64);
        compute(kbB, vb);
    }
    asm volatile("s_nop 7\n\ts_nop 7" ::: "memory");  // MFMA->VALU hazard guard (asm path)

    // l: sum over the 4 qd-lanes of each q column
    float lv0 = lp0, lv1 = lp1;
    lv0 += __shfl_xor(lv0, 16); lv0 += __shfl_xor(lv0, 32);
    lv1 += __shfl_xor(lv1, 16); lv1 += __shfl_xor(lv1, 32);
    if (lane < 16) { lred[w][0][lane] = lv0; lred[w][1][lane] = lv1; }
    if (ks == 1) {
#pragma unroll
        for (int qg = 0; qg < 2; qg++)
#pragma unroll
            for (int dvt = 0; dvt < 8; dvt++)
                *(f32x4*)&obuf[qh][qg][c][dvt * 16 + qd * 4] = oacc[qg][dvt];
    }
    __syncthreads();
    if (ks == 0) {
#pragma unroll
        for (int qg = 0; qg < 2; qg++) {
            float il = 1.0f / (lred[qh * 2][qg][c] + lred[qh * 2 + 1][qg][c]);
#pragma unroll
            for (int dvt = 0; dvt < 8; dvt++) {
                f32x4 v = oacc[qg][dvt] + *(const f32x4*)&obuf[qh][qg][c][dvt * 16 + qd * 4];
                bf16x4 o;
#pragma unroll
                for (int e = 0; e < 4; e++) o[e] = (__bf16)(v[e] * il);
                *(bf16x4*)(Og + (mq + qg * 16 + c) * D + dvt * 16 + qd * 4) = o;
            }
        }
    }
}

// ============================================================
// z = hf + O0 @ Vup0 + O1 @ Vup1   (fp32 residual + fp32 out)
// ============================================================
__launch_bounds__(256)
__global__ void k_gemm_vup(const __bf16* __restrict__ O, const __bf16* __restrict__ VupT,
                           const float* __restrict__ hf, float* __restrict__ z) {
    int n0 = blockIdx.y * 128;
    int m0 = blockIdx.x * 128;
    int w = threadIdx.x >> 6, lane = threadIdx.x & 63;
    int c = lane & 15, qd = lane >> 4;
    int mw = m0 + w * 32;

    f32x4 acc[2][8] = {};
#pragma unroll
    for (int kc = 0; kc < 8; kc++) {
        const __bf16* Oh = O + (kc >> 2) * (Nrows * D);
        const __bf16* Vh = VupT + (kc >> 2) * (L * D);
        int ko = (kc & 3) * 32 + qd * 8;
        bf16x8 a0 = *(const bf16x8*)(Oh + (mw + c) * D + ko);
        bf16x8 a1 = *(const bf16x8*)(Oh + (mw + 16 + c) * D + ko);
#pragma unroll
        for (int nt = 0; nt < 8; nt++) {
            bf16x8 b = *(const bf16x8*)(Vh + (n0 + nt * 16 + c) * D + ko);
            acc[0][nt] = MFMA16(a0, b, acc[0][nt]);
            acc[1][nt] = MFMA16(a1, b, acc[1][nt]);
        }
    }
#pragma unroll
    for (int mt = 0; mt < 2; mt++)
#pragma unroll
        for (int nt = 0; nt < 8; nt++)
#pragma unroll
            for (int r = 0; r < 4; r++) {
                int row = mw + mt * 16 + 4 * qd + r;
                int col = n0 + nt * 16 + c;
                z[row * L + col] = acc[mt][nt][r] + hf[row * L + col];
            }
}

// ============================================================
// out = relu(hin @ W^T + b); OutT = __bf16 (intermediate) or float (final)
// ============================================================
template <typename OutT>
__launch_bounds__(256)
__global__ void k_gemm_w(const __bf16* __restrict__ hin, const __bf16* __restrict__ W,
                         const float* __restrict__ bias, OutT* __restrict__ out) {
    int n0 = blockIdx.y * 128;
    int m0 = blockIdx.x * 128;
    int w = threadIdx.x >> 6, lane = threadIdx.x & 63;
    int c = lane & 15, qd = lane >> 4;
    int mw = m0 + w * 32;

    f32x4 acc[2][8] = {};
#pragma unroll
    for (int kc = 0; kc < 8; kc++) {
        bf16x8 a0 = *(const bf16x8*)(hin + (mw + c) * L + kc * 32 + qd * 8);
        bf16x8 a1 = *(const bf16x8*)(hin + (mw + 16 + c) * L + kc * 32 + qd * 8);
#pragma unroll
        for (int nt = 0; nt < 8; nt++) {
            bf16x8 b = *(const bf16x8*)(W + (n0 + nt * 16 + c) * L + kc * 32 + qd * 8);
            acc[0][nt] = MFMA16(a0, b, acc[0][nt]);
            acc[1][nt] = MFMA16(a1, b, acc[1][nt]);
        }
    }
#pragma unroll
    for (int mt = 0; mt < 2; mt++)
#pragma unroll
        for (int nt = 0; nt < 8; nt++) {
            int col = n0 + nt * 16 + c;
            float bv = bias[col];
#pragma unroll
            for (int r = 0; r < 4; r++) {
                int row = mw + mt * 16 + 4 * qd + r;
                float v = fmaxf(acc[mt][nt][r] + bv, 0.0f);
                out[row * L + col] = (OutT)v;
            }
        }
}

// ============================================================
extern "C" void kernel_launch(void* const* d_in, const int* in_sizes, int n_in,
                              void* d_out, int out_size, void* d_ws, size_t ws_size,
                              hipStream_t stream) {
    (void)in_sizes; (void)n_in; (void)out_size; (void)ws_size;
    const float* x   = (const float*)d_in[0];
    const float* Q   = (const float*)d_in[1];
    const float* K   = (const float*)d_in[2];
    const float* Vd  = (const float*)d_in[3];
    const float* Vup = (const float*)d_in[4];
    const float* W   = (const float*)d_in[5];
    const float* b   = (const float*)d_in[6];
    float* out = (float*)d_out;

    char* ws = (char*)d_ws;
    size_t off = 0;
    auto alloc = [&](size_t bytes) -> void* {
        void* p = ws + off;
        off += (bytes + 255) & ~(size_t)255;
        return p;
    };
    float*  stats = (float*)alloc(4 * 256 * sizeof(float)); // sum1,sq1,sum2,sq2
    __bf16* Bt    = (__bf16*)alloc(6 * 128 * 256 * 2);
    __bf16* VupT  = (__bf16*)alloc(2 * 256 * 128 * 2);
    __bf16* Wb    = (__bf16*)alloc(2 * 256 * 256 * 2);
    __bf16* hb    = (__bf16*)alloc((size_t)Nrows * L * 2);
    float*  hf    = (float*)alloc((size_t)Nrows * L * 4);
    __bf16* q0    = (__bf16*)alloc((size_t)Nrows * D * 2);
    __bf16* k0    = (__bf16*)alloc((size_t)Nrows * D * 2);
    __bf16* q1    = (__bf16*)alloc((size_t)Nrows * D * 2);
    __bf16* k1    = (__bf16*)alloc((size_t)Nrows * D * 2);
    __bf16* Vt    = (__bf16*)alloc((size_t)2 * 128 * Nrows * 2);
    __bf16* O     = (__bf16*)alloc((size_t)2 * Nrows * D * 2);
    float*  z     = (float*)alloc((size_t)Nrows * L * 4);
    __bf16* h2    = (__bf16*)alloc((size_t)Nrows * L * 2);
    __bf16* h3    = (__bf16*)alloc((size_t)Nrows * L * 2);

    float* sum1 = stats, *sq1 = stats + 256, *sum2 = stats + 512, *sq2 = stats + 768;

    hipMemsetAsync(stats, 0, 4 * 256 * sizeof(float), stream);
    k_cvt_params<<<1536, 256, 0, stream>>>(Q, K, Vd, Vup, W, Bt, VupT, Wb);
    k_bn_stats<<<128, 256, 0, stream>>>(x, sum1, sq1);
    k_bn_norm1<<<2048, 256, 0, stream>>>(x, sum1, sq1, hb, hf);
    k_gemm_qkv<<<dim3(64, 6), 256, 0, stream>>>(hb, Bt, q0, k0, q1, k1, Vt);
    k_flash<<<256, 256, 0, stream>>>(q0, k0, q1, k1, Vt, O);
    k_gemm_vup<<<dim3(64, 2), 256, 0, stream>>>(O, VupT, hf, z);
    k_bn_stats<<<128, 256, 0, stream>>>(z, sum2, sq2);
    k_bn_norm2<<<2048, 256, 0, stream>>>(z, sum2, sq2, h2);
    k_gemm_w<__bf16><<<dim3(64, 2), 256, 0, stream>>>(h2, Wb, b, h3);
    k_gemm_w<float><<<dim3(64, 2), 256, 0, stream>>>(h3, Wb + 256 * 256, b + 256, out);
}